// Round 1
// baseline (1695.896 us; speedup 1.0000x reference)
//
#include <hip/hip_runtime.h>

#define S_LEN 1024
#define DH 64
#define NBH 32
#define CROWS 1920               // 1024+512+256+128 coarse rows
#define HEAD_K (CROWS * DH)      // 122880 floats per head
#define ATTN_OFF (NBH * S_LEN * DH)  // 2097152 floats: start of combined_attention

// ---------------------------------------------------------------------------
// K1: pool K,V per scale; projK = pooled_k @ W^T + b   (torch Linear layout)
// grid = 32 heads * 30 coarse-row tiles (64 rows each), block 256
// ---------------------------------------------------------------------------
__global__ __launch_bounds__(256) void pool_project_kernel(
    const float* __restrict__ key, const float* __restrict__ value,
    const float* __restrict__ W, const float* __restrict__ b,
    float* __restrict__ projK, float* __restrict__ pv)
{
  __shared__ float Wl[64 * 65];   // W[si][e][d], padded
  __shared__ float pk[64 * 65];   // pooled K tile, padded
  const int t = threadIdx.x;
  const int bid = blockIdx.x;
  const int bh = bid / 30;
  const int tt = bid % 30;
  int si, jt;
  if (tt < 16)      { si = 0; jt = tt; }
  else if (tt < 24) { si = 1; jt = tt - 16; }
  else if (tt < 28) { si = 2; jt = tt - 24; }
  else              { si = 3; jt = tt - 28; }
  const int s = 1 << si;
  const int off = (si == 0) ? 0 : (si == 1) ? 1024 : (si == 2) ? 1536 : 1792;
  const int j0 = jt << 6;

  for (int i = t; i < 4096; i += 256)
    Wl[(i >> 6) * 65 + (i & 63)] = W[si * 4096 + i];

  const float* Kp = key + bh * (S_LEN * DH);
  const float* Vp = value + bh * (S_LEN * DH);
  const float invs = 1.0f / (float)s;
  for (int i = t; i < 4096; i += 256) {
    const int j = i >> 6, d = i & 63;
    const int fb = (j0 + j) * s;
    float ak = 0.f, av = 0.f;
    for (int f = 0; f < s; f++) {
      ak += Kp[(fb + f) * DH + d];
      av += Vp[(fb + f) * DH + d];
    }
    pk[j * 65 + d] = ak * invs;
    pv[bh * HEAD_K + (off + j0 + j) * DH + d] = av * invs;
  }
  __syncthreads();
  for (int i = t; i < 4096; i += 256) {
    const int j = i >> 6, e = i & 63;
    float acc = b[si * 64 + e];
    #pragma unroll 8
    for (int d = 0; d < 64; d++) acc += pk[j * 65 + d] * Wl[e * 65 + d];
    projK[bh * HEAD_K + (off + j0 + j) * DH + e] = acc;
  }
}

// ---------------------------------------------------------------------------
// K2: Mpv = U^T (U @ pv)  — the interp-coupling applied to pooled values.
// For s=1 U=I so Mpv=pv. One thread per (bh, coarse row, d).
// ---------------------------------------------------------------------------
__global__ __launch_bounds__(256) void mpv_kernel(
    const float* __restrict__ pv, float* __restrict__ Mpv)
{
  const int e = blockIdx.x * 256 + threadIdx.x;
  const int total = NBH * HEAD_K;
  if (e >= total) return;
  const int bh  = e / HEAD_K;
  const int rem = e - bh * HEAD_K;
  const int row = rem >> 6;
  const int d   = rem & 63;
  if (row < 1024) { Mpv[e] = pv[e]; return; }   // scale 1: identity
  int si, off;
  if (row < 1536)      { si = 1; off = 1024; }
  else if (row < 1792) { si = 2; off = 1536; }
  else                 { si = 3; off = 1792; }
  const int s = 1 << si;
  const int L = 1024 >> si;
  const int j = row - off;
  const float* pvs = pv + bh * HEAD_K + off * DH;   // [L][64]
  const float sf = (float)s;
  float acc = 0.f;
  const int klo = max(0, (j - 1) * s);
  const int khi = min(S_LEN - 1, (j + 2) * s);
  for (int k = klo; k <= khi; k++) {
    float srcp = (k + 0.5f) / sf - 0.5f;
    srcp = fminf(fmaxf(srcp, 0.f), (float)(L - 1));
    const int i0 = (int)floorf(srcp);
    const int i1 = min(i0 + 1, L - 1);
    const float w = srcp - (float)i0;
    float u = 0.f;
    if (i0 == j) u += 1.f - w;
    if (i1 == j) u += w;
    if (u != 0.f)
      acc += u * ((1.f - w) * pvs[i0 * DH + d] + w * pvs[i1 * DH + d]);
  }
  Mpv[e] = acc;
}

// ---------------------------------------------------------------------------
// K3: fused scores -> softmax (coarse probs in LDS) -> out = probs@Mpv
//     -> combined_attention via interp gather.
// grid = 32 heads * 128 q-tiles (8 rows), block 256. LDS = 78.3 KB -> 2 blk/CU
// ---------------------------------------------------------------------------
__global__ __launch_bounds__(256, 2) void fused_attn_kernel(
    const float* __restrict__ query, const float* __restrict__ projK,
    const float* __restrict__ Mpv, float* __restrict__ out)
{
  __shared__ float qs[8 * 64];       // Q tile
  __shared__ float pr[8 * 1920];     // coarse scores -> probs
  __shared__ float pkt[64 * 65];     // staging tile (projK / Mpv), padded
  const int t  = threadIdx.x;
  const int bh = blockIdx.x >> 7;
  const int qt = blockIdx.x & 127;
  const int q0 = qt << 3;
  const int r  = t >> 5;             // row 0..7 (32-thread group per row)
  const int jg = t & 31;

  const float* qbase = query + bh * (S_LEN * DH) + q0 * DH;
  for (int i = t; i < 512; i += 256) qs[i] = qbase[i];
  __syncthreads();

  // ---- P1: scores (coarse), all scales ----
  const float* pkh = projK + bh * HEAD_K;
  #pragma unroll
  for (int si = 0; si < 4; si++) {
    const int L   = 1024 >> si;
    const int off = (si == 0) ? 0 : (si == 1) ? 1024 : (si == 2) ? 1536 : 1792;
    for (int jt = 0; jt < (L >> 6); jt++) {
      const float* src = pkh + (off + (jt << 6)) * DH;
      __syncthreads();
      for (int i = t; i < 4096; i += 256)
        pkt[(i >> 6) * 65 + (i & 63)] = src[i];
      __syncthreads();
      float a0 = 0.f, a1 = 0.f;
      const float* qr = qs + r * 64;
      #pragma unroll
      for (int d = 0; d < 64; d++) {
        const float qv = qr[d];
        a0 += qv * pkt[jg * 65 + d];
        a1 += qv * pkt[(jg + 32) * 65 + d];
      }
      pr[r * 1920 + off + (jt << 6) + jg]      = a0 * 0.125f;
      pr[r * 1920 + off + (jt << 6) + jg + 32] = a1 * 0.125f;
    }
  }
  __syncthreads();

  // ---- P2: per-row per-scale softmax in LDS ----
  float* prr = pr + r * 1920;
  #pragma unroll
  for (int si = 0; si < 4; si++) {
    const int L   = 1024 >> si;
    const int off = (si == 0) ? 0 : (si == 1) ? 1024 : (si == 2) ? 1536 : 1792;
    float m = -1e30f;
    for (int j = jg; j < L; j += 32) m = fmaxf(m, prr[off + j]);
    #pragma unroll
    for (int dlt = 16; dlt >= 1; dlt >>= 1) m = fmaxf(m, __shfl_xor(m, dlt));
    float ssum = 0.f;
    for (int j = jg; j < L; j += 32) {
      const float ev = __expf(prr[off + j] - m);
      prr[off + j] = ev;
      ssum += ev;
    }
    #pragma unroll
    for (int dlt = 16; dlt >= 1; dlt >>= 1) ssum += __shfl_xor(ssum, dlt);
    const float inv = 1.0f / ssum;
    for (int j = jg; j < L; j += 32) prr[off + j] *= inv;
  }

  // ---- P3: out = 0.25 * sum_s probs_s @ Mpv_s  (coarse resolution) ----
  const float* mvh = Mpv + bh * HEAD_K;
  float o0 = 0.f, o1 = 0.f;
  #pragma unroll
  for (int si = 0; si < 4; si++) {
    const int L   = 1024 >> si;
    const int off = (si == 0) ? 0 : (si == 1) ? 1024 : (si == 2) ? 1536 : 1792;
    for (int jt = 0; jt < (L >> 6); jt++) {
      const float* src = mvh + (off + (jt << 6)) * DH;
      __syncthreads();
      for (int i = t; i < 4096; i += 256)
        pkt[(i >> 6) * 65 + (i & 63)] = src[i];
      __syncthreads();
      const float* prt = pr + r * 1920 + off + (jt << 6);
      #pragma unroll
      for (int jj = 0; jj < 64; jj++) {
        const float p = prt[jj];
        o0 += p * pkt[jj * 65 + jg];
        o1 += p * pkt[jj * 65 + jg + 32];
      }
    }
  }
  {
    float* ob = out + bh * (S_LEN * DH) + q0 * DH;
    ob[r * 64 + jg]      = o0 * 0.25f;
    ob[r * 64 + jg + 32] = o1 * 0.25f;
  }

  // ---- P4: combined_attention = 0.25 * sum_s interp(probs_s) ----
  __syncthreads();
  float* ab = out + ATTN_OFF + bh * (S_LEN * S_LEN) + q0 * S_LEN;
  for (int rep = 0; rep < 32; rep++) {
    const int idx = rep * 256 + t;      // 0..8191 over [8 rows][1024 keys]
    const int rr = idx >> 10;
    const int k  = idx & 1023;
    const float* p2 = pr + rr * 1920;
    float acc = p2[k];                  // s = 1: no interp
    #pragma unroll
    for (int si = 1; si < 4; si++) {
      const int L   = 1024 >> si;
      const int off = (si == 1) ? 1024 : (si == 2) ? 1536 : 1792;
      const float sf = (float)(1 << si);
      float srcp = (k + 0.5f) / sf - 0.5f;
      srcp = fminf(fmaxf(srcp, 0.f), (float)(L - 1));
      const int i0 = (int)floorf(srcp);
      const int i1 = min(i0 + 1, L - 1);
      const float w = srcp - (float)i0;
      acc += (1.f - w) * p2[off + i0] + w * p2[off + i1];
    }
    ab[idx] = acc * 0.25f;
  }
}

// ---------------------------------------------------------------------------
extern "C" void kernel_launch(void* const* d_in, const int* in_sizes, int n_in,
                              void* d_out, int out_size, void* d_ws, size_t ws_size,
                              hipStream_t stream) {
  (void)in_sizes; (void)n_in; (void)out_size; (void)ws_size;
  const float* query = (const float*)d_in[0];
  const float* key   = (const float*)d_in[1];
  const float* value = (const float*)d_in[2];
  const float* W     = (const float*)d_in[3];
  const float* b     = (const float*)d_in[4];
  float* out = (float*)d_out;

  float* projK = (float*)d_ws;                 // 32*1920*64 floats
  float* pv    = projK + (size_t)NBH * HEAD_K; // pooled values
  float* Mpv   = pv    + (size_t)NBH * HEAD_K; // U^T U pv

  pool_project_kernel<<<NBH * 30, 256, 0, stream>>>(key, value, W, b, projK, pv);
  mpv_kernel<<<(NBH * HEAD_K + 255) / 256, 256, 0, stream>>>(pv, Mpv);
  fused_attn_kernel<<<NBH * 128, 256, 0, stream>>>(query, projK, Mpv, out);
}

// Round 2
// 628.270 us; speedup vs baseline: 2.6993x; 2.6993x over previous
//
#include <hip/hip_runtime.h>

#define S_LEN 1024
#define DH 64
#define NBH 32
#define CROWS 1920               // 1024+512+256+128 coarse rows
#define HEAD_K (CROWS * DH)      // 122880 floats per head
#define ATTN_OFF (NBH * S_LEN * DH)  // start of combined_attention in d_out

// ---------------------------------------------------------------------------
// K1: pool K,V per scale; projKT[bh][d][1920] = (pooled_k @ W^T + b)^T
// grid = 32 heads * 30 coarse-row tiles (64 rows each), block 256
// ---------------------------------------------------------------------------
__global__ __launch_bounds__(256) void pool_project_kernel(
    const float* __restrict__ key, const float* __restrict__ value,
    const float* __restrict__ W, const float* __restrict__ b,
    float* __restrict__ projKT, float* __restrict__ pv)
{
  __shared__ float Wl[64 * 68];   // W[si][e][d], stride 68 (b128-aligned, low conflict)
  __shared__ float pk[64 * 68];   // pooled K tile
  const int t = threadIdx.x;
  const int bid = blockIdx.x;
  const int bh = bid / 30;
  const int tt = bid % 30;
  int si, jt;
  if (tt < 16)      { si = 0; jt = tt; }
  else if (tt < 24) { si = 1; jt = tt - 16; }
  else if (tt < 28) { si = 2; jt = tt - 24; }
  else              { si = 3; jt = tt - 28; }
  const int s = 1 << si;
  const int off = (si == 0) ? 0 : (si == 1) ? 1024 : (si == 2) ? 1536 : 1792;
  const int j0 = jt << 6;

  for (int i = t; i < 4096; i += 256)
    Wl[(i >> 6) * 68 + (i & 63)] = W[si * 4096 + i];

  const float* Kp = key + bh * (S_LEN * DH);
  const float* Vp = value + bh * (S_LEN * DH);
  const float invs = 1.0f / (float)s;
  for (int i = t; i < 4096; i += 256) {
    const int j = i >> 6, d = i & 63;
    const int fb = (j0 + j) * s;
    float ak = 0.f, av = 0.f;
    for (int f = 0; f < s; f++) {
      ak += Kp[(fb + f) * DH + d];
      av += Vp[(fb + f) * DH + d];
    }
    pk[j * 68 + d] = ak * invs;
    pv[bh * HEAD_K + (off + j0 + j) * DH + d] = av * invs;
  }
  __syncthreads();

  // register-blocked projection: thread = (j = t&63, e-group of 16)
  const int j  = t & 63;
  const int e0 = (t >> 6) << 4;
  float acc[16];
  #pragma unroll
  for (int ee = 0; ee < 16; ee++) acc[ee] = b[si * 64 + e0 + ee];
  #pragma unroll
  for (int dq = 0; dq < 16; dq++) {
    const float4 p4 = *(const float4*)&pk[j * 68 + dq * 4];
    #pragma unroll
    for (int ee = 0; ee < 16; ee++) {
      const float4 w4 = *(const float4*)&Wl[(e0 + ee) * 68 + dq * 4];
      acc[ee] += p4.x * w4.x + p4.y * w4.y + p4.z * w4.z + p4.w * w4.w;
    }
  }
  const int ck = off + j0 + j;
  float* dst = projKT + bh * HEAD_K + ck;
  #pragma unroll
  for (int ee = 0; ee < 16; ee++) dst[(e0 + ee) * 1920] = acc[ee];
}

// ---------------------------------------------------------------------------
// K2: Mpv = U^T (U @ pv). For s=1 U=I so Mpv=pv. One thread per element.
// ---------------------------------------------------------------------------
__global__ __launch_bounds__(256) void mpv_kernel(
    const float* __restrict__ pv, float* __restrict__ Mpv)
{
  const int e = blockIdx.x * 256 + threadIdx.x;
  const int total = NBH * HEAD_K;
  if (e >= total) return;
  const int bh  = e / HEAD_K;
  const int rem = e - bh * HEAD_K;
  const int row = rem >> 6;
  const int d   = rem & 63;
  if (row < 1024) { Mpv[e] = pv[e]; return; }
  int si, off;
  if (row < 1536)      { si = 1; off = 1024; }
  else if (row < 1792) { si = 2; off = 1536; }
  else                 { si = 3; off = 1792; }
  const int s = 1 << si;
  const int L = 1024 >> si;
  const int j = row - off;
  const float* pvs = pv + bh * HEAD_K + off * DH;
  const float sf = (float)s;
  float acc = 0.f;
  const int klo = max(0, (j - 1) * s);
  const int khi = min(S_LEN - 1, (j + 2) * s);
  for (int k = klo; k <= khi; k++) {
    float srcp = (k + 0.5f) / sf - 0.5f;
    srcp = fminf(fmaxf(srcp, 0.f), (float)(L - 1));
    const int i0 = (int)floorf(srcp);
    const int i1 = min(i0 + 1, L - 1);
    const float w = srcp - (float)i0;
    float u = 0.f;
    if (i0 == j) u += 1.f - w;
    if (i1 == j) u += w;
    if (u != 0.f)
      acc += u * ((1.f - w) * pvs[i0 * DH + d] + w * pvs[i1 * DH + d]);
  }
  Mpv[e] = acc;
}

// ---------------------------------------------------------------------------
// K3: fused scores -> softmax -> out = probs@Mpv -> attention interp-gather.
// Register-blocked: 8 q rows live in VGPRs; projKT/Mpv streamed from L2.
// grid = 128 q-tiles * 32 heads (head fastest => same-head blocks same XCD).
// LDS = 61440 (probs) + 16384 (q | reduction) = 77824 B -> 2 blocks/CU.
// ---------------------------------------------------------------------------
__global__ __launch_bounds__(256, 2) void fused_attn_kernel(
    const float* __restrict__ query, const float* __restrict__ projKT,
    const float* __restrict__ Mpv, float* __restrict__ out)
{
  __shared__ float pr[8 * 1920];     // coarse scores -> probs
  __shared__ float aux[4096];        // q tile during P1; reduction buf in P3
  const int t  = threadIdx.x;
  const int bh = blockIdx.x & 31;
  const int qt = blockIdx.x >> 5;
  const int q0 = qt << 3;

  const float* qbase = query + bh * (S_LEN * DH) + q0 * DH;
  for (int i = t; i < 512; i += 256) aux[i] = qbase[i];
  __syncthreads();

  // ---- P1: scores. Thread owns 8 rows x 8 keys (4t..4t+3, 1024+4t..+3) ----
  const float* pkh = projKT + bh * HEAD_K;     // [64 d][1920 k]
  {
    float acc0[8][4], acc1[8][4];
    #pragma unroll
    for (int r = 0; r < 8; r++)
      #pragma unroll
      for (int c = 0; c < 4; c++) { acc0[r][c] = 0.f; acc1[r][c] = 0.f; }
    const bool act1 = (t < 224);
    const int ck0 = 4 * t;
    const int ck1 = 1024 + 4 * t;
    for (int dg = 0; dg < 8; dg++) {
      float qv[8][8];
      #pragma unroll
      for (int r = 0; r < 8; r++) {
        const float4 a  = *(const float4*)&aux[r * 64 + dg * 8];
        const float4 bq = *(const float4*)&aux[r * 64 + dg * 8 + 4];
        qv[r][0] = a.x;  qv[r][1] = a.y;  qv[r][2] = a.z;  qv[r][3] = a.w;
        qv[r][4] = bq.x; qv[r][5] = bq.y; qv[r][6] = bq.z; qv[r][7] = bq.w;
      }
      #pragma unroll
      for (int dd = 0; dd < 8; dd++) {
        const int d = dg * 8 + dd;
        const float4 k0v = *(const float4*)&pkh[d * 1920 + ck0];
        #pragma unroll
        for (int r = 0; r < 8; r++) {
          acc0[r][0] += qv[r][dd] * k0v.x;
          acc0[r][1] += qv[r][dd] * k0v.y;
          acc0[r][2] += qv[r][dd] * k0v.z;
          acc0[r][3] += qv[r][dd] * k0v.w;
        }
        if (act1) {
          const float4 k1v = *(const float4*)&pkh[d * 1920 + ck1];
          #pragma unroll
          for (int r = 0; r < 8; r++) {
            acc1[r][0] += qv[r][dd] * k1v.x;
            acc1[r][1] += qv[r][dd] * k1v.y;
            acc1[r][2] += qv[r][dd] * k1v.z;
            acc1[r][3] += qv[r][dd] * k1v.w;
          }
        }
      }
    }
    #pragma unroll
    for (int r = 0; r < 8; r++)
      *(float4*)&pr[r * 1920 + ck0] =
        make_float4(acc0[r][0] * 0.125f, acc0[r][1] * 0.125f,
                    acc0[r][2] * 0.125f, acc0[r][3] * 0.125f);
    if (act1) {
      #pragma unroll
      for (int r = 0; r < 8; r++)
        *(float4*)&pr[r * 1920 + ck1] =
          make_float4(acc1[r][0] * 0.125f, acc1[r][1] * 0.125f,
                      acc1[r][2] * 0.125f, acc1[r][3] * 0.125f);
    }
  }
  __syncthreads();

  // ---- P2: per-row per-scale softmax in LDS ----
  {
    const int r  = t >> 5;
    const int jg = t & 31;
    float* prr = pr + r * 1920;
    #pragma unroll
    for (int si = 0; si < 4; si++) {
      const int L   = 1024 >> si;
      const int off = (si == 0) ? 0 : (si == 1) ? 1024 : (si == 2) ? 1536 : 1792;
      float m = -1e30f;
      for (int jj = jg; jj < L; jj += 32) m = fmaxf(m, prr[off + jj]);
      #pragma unroll
      for (int dlt = 16; dlt >= 1; dlt >>= 1) m = fmaxf(m, __shfl_xor(m, dlt));
      float ssum = 0.f;
      for (int jj = jg; jj < L; jj += 32) {
        const float ev = __expf(prr[off + jj] - m);
        prr[off + jj] = ev;
        ssum += ev;
      }
      #pragma unroll
      for (int dlt = 16; dlt >= 1; dlt >>= 1) ssum += __shfl_xor(ssum, dlt);
      const float inv = 1.0f / ssum;
      for (int jj = jg; jj < L; jj += 32) prr[off + jj] *= inv;
    }
  }
  __syncthreads();

  // ---- P3: out = 0.25 * probs @ Mpv. Thread = (d-pair, k-segment of 240) --
  {
    const int dpair = t & 31;
    const int kseg  = t >> 5;
    const float* mvh = Mpv + bh * HEAD_K;      // [1920 k][64 d]
    float acc[8][2];
    #pragma unroll
    for (int r = 0; r < 8; r++) { acc[r][0] = 0.f; acc[r][1] = 0.f; }
    const int kbase = kseg * 240;
    for (int ch = 0; ch < 30; ch++) {
      const int k0 = kbase + ch * 8;
      float pv8[8][8];
      #pragma unroll
      for (int r = 0; r < 8; r++) {
        const float4 a  = *(const float4*)&pr[r * 1920 + k0];
        const float4 bq = *(const float4*)&pr[r * 1920 + k0 + 4];
        pv8[r][0] = a.x;  pv8[r][1] = a.y;  pv8[r][2] = a.z;  pv8[r][3] = a.w;
        pv8[r][4] = bq.x; pv8[r][5] = bq.y; pv8[r][6] = bq.z; pv8[r][7] = bq.w;
      }
      #pragma unroll
      for (int kk = 0; kk < 8; kk++) {
        const float2 mv = *(const float2*)&mvh[(k0 + kk) * 64 + 2 * dpair];
        #pragma unroll
        for (int r = 0; r < 8; r++) {
          acc[r][0] += pv8[r][kk] * mv.x;
          acc[r][1] += pv8[r][kk] * mv.y;
        }
      }
    }
    // cross-segment reduction via aux (q tile is dead now)
    #pragma unroll
    for (int r = 0; r < 8; r++)
      *(float2*)&aux[kseg * 512 + r * 64 + 2 * dpair] =
        make_float2(acc[r][0], acc[r][1]);
    __syncthreads();
    float* ob = out + bh * (S_LEN * DH) + q0 * DH;
    #pragma unroll
    for (int rep = 0; rep < 2; rep++) {
      const int idx = rep * 256 + t;
      float ssum = 0.f;
      #pragma unroll
      for (int seg = 0; seg < 8; seg++) ssum += aux[seg * 512 + idx];
      ob[idx] = ssum * 0.25f;
    }
  }

  // ---- P4: combined_attention = 0.25 * sum_s interp(probs_s) ----
  float* ab = out + ATTN_OFF + bh * (S_LEN * S_LEN) + q0 * S_LEN;
  for (int rep = 0; rep < 8; rep++) {
    const int e  = rep * 256 + t;          // float4 index in [0,2048)
    const int rr = e >> 8;
    const int k0 = (e & 255) << 2;
    const float* p2 = pr + rr * 1920;
    const float4 base = *(const float4*)&p2[k0];
    float res[4] = {base.x, base.y, base.z, base.w};
    #pragma unroll
    for (int si = 1; si < 4; si++) {
      const int   L     = 1024 >> si;
      const int   off2  = (si == 1) ? 1024 : (si == 2) ? 1536 : 1792;
      const float inv_s = (si == 1) ? 0.5f : (si == 2) ? 0.25f : 0.125f;
      #pragma unroll
      for (int kk = 0; kk < 4; kk++) {
        float srcp = ((float)(k0 + kk) + 0.5f) * inv_s - 0.5f;
        srcp = fminf(fmaxf(srcp, 0.f), (float)(L - 1));
        const int i0 = (int)floorf(srcp);
        const int i1 = min(i0 + 1, L - 1);
        const float w = srcp - (float)i0;
        res[kk] += (1.f - w) * p2[off2 + i0] + w * p2[off2 + i1];
      }
    }
    *(float4*)&ab[e << 2] = make_float4(res[0] * 0.25f, res[1] * 0.25f,
                                        res[2] * 0.25f, res[3] * 0.25f);
  }
}

// ---------------------------------------------------------------------------
extern "C" void kernel_launch(void* const* d_in, const int* in_sizes, int n_in,
                              void* d_out, int out_size, void* d_ws, size_t ws_size,
                              hipStream_t stream) {
  (void)in_sizes; (void)n_in; (void)out_size; (void)ws_size;
  const float* query = (const float*)d_in[0];
  const float* key   = (const float*)d_in[1];
  const float* value = (const float*)d_in[2];
  const float* W     = (const float*)d_in[3];
  const float* b     = (const float*)d_in[4];
  float* out = (float*)d_out;

  float* projKT = (float*)d_ws;                  // [32][64][1920]
  float* pv     = projKT + (size_t)NBH * HEAD_K; // [32][1920][64]
  float* Mpv    = pv     + (size_t)NBH * HEAD_K; // [32][1920][64]

  pool_project_kernel<<<NBH * 30, 256, 0, stream>>>(key, value, W, b, projKT, pv);
  mpv_kernel<<<(NBH * HEAD_K + 255) / 256, 256, 0, stream>>>(pv, Mpv);
  fused_attn_kernel<<<NBH * 128, 256, 0, stream>>>(query, projKT, Mpv, out);
}

// Round 3
// 371.090 us; speedup vs baseline: 4.5700x; 1.6930x over previous
//
#include <hip/hip_runtime.h>

#define S_LEN 1024
#define DH 64
#define NBH 32
#define CROWS 1920                   // 1024+512+256+128 coarse rows
#define HEAD_K (CROWS * DH)          // 122880 elements per head (fp32 or packed bf16)
#define NCHUNK (HEAD_K / 8)          // 15360 16-byte fragment chunks per head
#define ATTN_OFF (NBH * S_LEN * DH)  // start of combined_attention in d_out
#define PSTR 1928                    // LDS probs row stride (bf16 elems, padded)

typedef __attribute__((ext_vector_type(8))) short bf8_t;
typedef __attribute__((ext_vector_type(4))) float f32x4_t;

__device__ __forceinline__ unsigned short f2bf(float x) {
  unsigned u = __float_as_uint(x);
  u += 0x7fffu + ((u >> 16) & 1u);
  return (unsigned short)(u >> 16);
}
__device__ __forceinline__ float bf2f(unsigned short h) {
  return __uint_as_float(((unsigned)h) << 16);
}

// ---------------------------------------------------------------------------
// K1: pool K,V; proj = pooled_k @ W^T + b; write pv fp32 and projB packed in
// MFMA-B-frag order: chunk[(kt*2+db)*64+lane][j] = proj[kt*16+(lane&15)]
//                                                      [db*32+(lane>>4)*8+j]
// ---------------------------------------------------------------------------
__global__ __launch_bounds__(256) void pool_project_kernel(
    const float* __restrict__ key, const float* __restrict__ value,
    const float* __restrict__ W, const float* __restrict__ b,
    unsigned short* __restrict__ projB, float* __restrict__ pv)
{
  __shared__ __align__(16) float Wl[64 * 68];
  __shared__ __align__(16) float pk[64 * 68];
  __shared__ __align__(16) float prL[64 * 68];   // proj results [key][e]
  const int t = threadIdx.x;
  const int bid = blockIdx.x;
  const int bh = bid / 30;
  const int tt = bid % 30;
  int si, jt;
  if (tt < 16)      { si = 0; jt = tt; }
  else if (tt < 24) { si = 1; jt = tt - 16; }
  else if (tt < 28) { si = 2; jt = tt - 24; }
  else              { si = 3; jt = tt - 28; }
  const int s = 1 << si;
  const int off = (si == 0) ? 0 : (si == 1) ? 1024 : (si == 2) ? 1536 : 1792;
  const int j0 = jt << 6;

  for (int i = t; i < 4096; i += 256)
    Wl[(i >> 6) * 68 + (i & 63)] = W[si * 4096 + i];

  const float* Kp = key + bh * (S_LEN * DH);
  const float* Vp = value + bh * (S_LEN * DH);
  const float invs = 1.0f / (float)s;
  for (int i = t; i < 4096; i += 256) {
    const int j = i >> 6, d = i & 63;
    const int fb = (j0 + j) * s;
    float ak = 0.f, av = 0.f;
    for (int f = 0; f < s; f++) {
      ak += Kp[(fb + f) * DH + d];
      av += Vp[(fb + f) * DH + d];
    }
    pk[j * 68 + d] = ak * invs;
    pv[bh * HEAD_K + (off + j0 + j) * DH + d] = av * invs;
  }
  __syncthreads();

  // register-blocked projection into prL
  {
    const int j  = t & 63;
    const int e0 = (t >> 6) << 4;
    float acc[16];
    #pragma unroll
    for (int ee = 0; ee < 16; ee++) acc[ee] = b[si * 64 + e0 + ee];
    #pragma unroll
    for (int dq = 0; dq < 16; dq++) {
      const float4 p4 = *(const float4*)&pk[j * 68 + dq * 4];
      #pragma unroll
      for (int ee = 0; ee < 16; ee++) {
        const float4 w4 = *(const float4*)&Wl[(e0 + ee) * 68 + dq * 4];
        acc[ee] += p4.x * w4.x + p4.y * w4.y + p4.z * w4.z + p4.w * w4.w;
      }
    }
    #pragma unroll
    for (int ee = 0; ee < 16; ee++) prL[j * 68 + e0 + ee] = acc[ee];
  }
  __syncthreads();

  // pack 4 ktiles x 2 dblk x 64 lanes = 512 chunks, bf16
  const int ktg0 = (off + j0) >> 4;
  for (int c = t; c < 512; c += 256) {
    const int ktl = c >> 7;
    const int db  = (c >> 6) & 1;
    const int ln  = c & 63;
    const int kl  = ktl * 16 + (ln & 15);
    const int e0p = db * 32 + ((ln >> 4) & 3) * 8;
    const float4 a = *(const float4*)&prL[kl * 68 + e0p];
    const float4 c4 = *(const float4*)&prL[kl * 68 + e0p + 4];
    bf8_t v;
    v[0] = (short)f2bf(a.x);  v[1] = (short)f2bf(a.y);
    v[2] = (short)f2bf(a.z);  v[3] = (short)f2bf(a.w);
    v[4] = (short)f2bf(c4.x); v[5] = (short)f2bf(c4.y);
    v[6] = (short)f2bf(c4.z); v[7] = (short)f2bf(c4.w);
    ((bf8_t*)projB)[bh * NCHUNK + ((ktg0 + ktl) * 2 + db) * 64 + ln] = v;
  }
}

// ---------------------------------------------------------------------------
// K2: Mpv = U^T U pv, written directly as packed MFMA-B frags (bf16):
// chunk[(kb*4+nt)*64+lane][j] = Mpv[kb*32+(lane>>4)*8+j][nt*16+(lane&15)]
// One thread per 16B chunk.
// ---------------------------------------------------------------------------
__global__ __launch_bounds__(256) void mpv_pack_kernel(
    const float* __restrict__ pv, unsigned short* __restrict__ mpvB)
{
  const int g = blockIdx.x * 256 + threadIdx.x;   // chunk id
  const int bh  = g / NCHUNK;
  const int rem = g - bh * NCHUNK;
  const int kb  = rem >> 8;                       // 0..59
  const int nt  = (rem >> 6) & 3;
  const int ln  = rem & 63;
  const int d   = nt * 16 + (ln & 15);
  const int k0  = kb * 32 + ((ln >> 4) & 3) * 8;  // coarse row base, 8-run
  const float* pvh = pv + bh * HEAD_K;
  bf8_t v;
  if (k0 < 1024) {                                // scale 1: identity
    #pragma unroll
    for (int j = 0; j < 8; j++) v[j] = (short)f2bf(pvh[(k0 + j) * DH + d]);
  } else {
    int si, off;
    if (k0 < 1536)      { si = 1; off = 1024; }
    else if (k0 < 1792) { si = 2; off = 1536; }
    else                { si = 3; off = 1792; }
    const int s = 1 << si;
    const int L = 1024 >> si;
    const float inv_s = 1.0f / (float)s;
    const float* pvs = pvh + off * DH;
    #pragma unroll
    for (int j = 0; j < 8; j++) {
      const int jloc = k0 + j - off;
      float acc = 0.f;
      const int klo = max(0, (jloc - 1) * s);
      const int khi = min(S_LEN - 1, (jloc + 2) * s);
      for (int kf = klo; kf <= khi; kf++) {
        float srcp = ((float)kf + 0.5f) * inv_s - 0.5f;
        srcp = fminf(fmaxf(srcp, 0.f), (float)(L - 1));
        const int i0 = (int)floorf(srcp);
        const int i1 = min(i0 + 1, L - 1);
        const float w = srcp - (float)i0;
        float u = 0.f;
        if (i0 == jloc) u += 1.f - w;
        if (i1 == jloc) u += w;
        if (u != 0.f)
          acc += u * ((1.f - w) * pvs[i0 * DH + d] + w * pvs[i1 * DH + d]);
      }
      v[j] = (short)f2bf(acc);
    }
  }
  ((bf8_t*)mpvB)[g] = v;
}

// ---------------------------------------------------------------------------
// K3: MFMA scores -> bf16 probs in LDS -> MFMA out -> interp-gather attention.
// 16 q-rows per block; grid = 64 q-tiles * 32 heads; 256 thr; LDS 61.7 KB.
// ---------------------------------------------------------------------------
__global__ __launch_bounds__(256, 2) void fused_attn_kernel(
    const float* __restrict__ query, const unsigned short* __restrict__ projB,
    const unsigned short* __restrict__ mpvB, float* __restrict__ out)
{
  __shared__ __align__(16) unsigned short prbf[16 * PSTR];
  const int t    = threadIdx.x;
  const int bh   = blockIdx.x & 31;
  const int qt   = blockIdx.x >> 5;
  const int q0   = qt << 4;
  const int wave = t >> 6;
  const int lane = t & 63;
  const int quad = lane >> 4;
  const int n16  = lane & 15;

  // A-frags: A[m=lane&15][k=quad*8+j], k = d (+32 for second frag)
  bf8_t af0, af1;
  {
    const float* qrow = query + bh * (S_LEN * DH) + (q0 + n16) * DH;
    const float4 a0 = *(const float4*)(qrow + quad * 8);
    const float4 a1 = *(const float4*)(qrow + quad * 8 + 4);
    const float4 a2 = *(const float4*)(qrow + 32 + quad * 8);
    const float4 a3 = *(const float4*)(qrow + 32 + quad * 8 + 4);
    af0[0] = (short)f2bf(a0.x); af0[1] = (short)f2bf(a0.y);
    af0[2] = (short)f2bf(a0.z); af0[3] = (short)f2bf(a0.w);
    af0[4] = (short)f2bf(a1.x); af0[5] = (short)f2bf(a1.y);
    af0[6] = (short)f2bf(a1.z); af0[7] = (short)f2bf(a1.w);
    af1[0] = (short)f2bf(a2.x); af1[1] = (short)f2bf(a2.y);
    af1[2] = (short)f2bf(a2.z); af1[3] = (short)f2bf(a2.w);
    af1[4] = (short)f2bf(a3.x); af1[5] = (short)f2bf(a3.y);
    af1[6] = (short)f2bf(a3.z); af1[7] = (short)f2bf(a3.w);
  }

  // ---- P1: scores via MFMA; write bf16 to LDS ----
  {
    const bf8_t* pB = (const bf8_t*)projB + bh * NCHUNK;
    for (int kt = wave; kt < 120; kt += 4) {
      const bf8_t b0 = pB[(kt * 2 + 0) * 64 + lane];
      const bf8_t b1 = pB[(kt * 2 + 1) * 64 + lane];
      f32x4_t c = {0.f, 0.f, 0.f, 0.f};
      c = __builtin_amdgcn_mfma_f32_16x16x32_bf16(af0, b0, c, 0, 0, 0);
      c = __builtin_amdgcn_mfma_f32_16x16x32_bf16(af1, b1, c, 0, 0, 0);
      const int col = kt * 16 + n16;
      #pragma unroll
      for (int i = 0; i < 4; i++)
        prbf[(quad * 4 + i) * PSTR + col] = f2bf(c[i] * 0.125f);
    }
  }
  __syncthreads();

  // ---- P2: per-row per-scale softmax (bf16 in LDS, fp32 math) ----
  {
    const int rr = t >> 4;
    const int g  = t & 15;
    unsigned short* prr = prbf + rr * PSTR;
    #pragma unroll
    for (int si = 0; si < 4; si++) {
      const int L   = 1024 >> si;
      const int off = (si == 0) ? 0 : (si == 1) ? 1024 : (si == 2) ? 1536 : 1792;
      const int nch = L >> 2;
      float m = -1e30f;
      for (int ch = g; ch < nch; ch += 16) {
        const ushort4 u = *(const ushort4*)(prr + off + ch * 4);
        m = fmaxf(m, fmaxf(fmaxf(bf2f(u.x), bf2f(u.y)),
                           fmaxf(bf2f(u.z), bf2f(u.w))));
      }
      #pragma unroll
      for (int dlt = 8; dlt >= 1; dlt >>= 1) m = fmaxf(m, __shfl_xor(m, dlt));
      float ssum = 0.f;
      for (int ch = g; ch < nch; ch += 16) {
        ushort4 u = *(const ushort4*)(prr + off + ch * 4);
        const float e0 = __expf(bf2f(u.x) - m);
        const float e1 = __expf(bf2f(u.y) - m);
        const float e2 = __expf(bf2f(u.z) - m);
        const float e3 = __expf(bf2f(u.w) - m);
        ssum += (e0 + e1) + (e2 + e3);
        u.x = f2bf(e0); u.y = f2bf(e1); u.z = f2bf(e2); u.w = f2bf(e3);
        *(ushort4*)(prr + off + ch * 4) = u;
      }
      #pragma unroll
      for (int dlt = 8; dlt >= 1; dlt >>= 1) ssum += __shfl_xor(ssum, dlt);
      const float inv = 1.0f / ssum;
      for (int ch = g; ch < nch; ch += 16) {
        ushort4 u = *(const ushort4*)(prr + off + ch * 4);
        u.x = f2bf(bf2f(u.x) * inv); u.y = f2bf(bf2f(u.y) * inv);
        u.z = f2bf(bf2f(u.z) * inv); u.w = f2bf(bf2f(u.w) * inv);
        *(ushort4*)(prr + off + ch * 4) = u;
      }
    }
  }
  __syncthreads();

  // ---- P3: out = 0.25 * probs @ Mpv via MFMA (wave owns d-tile nt=wave) ----
  {
    const bf8_t* pM = (const bf8_t*)mpvB + bh * NCHUNK;
    f32x4_t acc = {0.f, 0.f, 0.f, 0.f};
    for (int kb = 0; kb < 60; kb++) {
      const bf8_t a = *(const bf8_t*)(prbf + n16 * PSTR + kb * 32 + quad * 8);
      const bf8_t bb = pM[(kb * 4 + wave) * 64 + lane];
      acc = __builtin_amdgcn_mfma_f32_16x16x32_bf16(a, bb, acc, 0, 0, 0);
    }
    float* ob = out + bh * (S_LEN * DH) + q0 * DH;
    #pragma unroll
    for (int i = 0; i < 4; i++)
      ob[(quad * 4 + i) * DH + wave * 16 + n16] = acc[i] * 0.25f;
  }

  // ---- P4: combined_attention = 0.25 * sum_s interp(probs_s) ----
  float* ab = out + ATTN_OFF + (size_t)bh * (S_LEN * S_LEN) + (size_t)q0 * S_LEN;
  for (int rep = 0; rep < 16; rep++) {
    const int idx = rep * 256 + t;        // float4 chunk id, 0..4095
    const int rr  = idx >> 8;
    const int k0  = (idx & 255) << 2;
    const unsigned short* p2 = prbf + rr * PSTR;
    const ushort4 bs = *(const ushort4*)(p2 + k0);
    float res[4] = {bf2f(bs.x), bf2f(bs.y), bf2f(bs.z), bf2f(bs.w)};
    #pragma unroll
    for (int si = 1; si < 4; si++) {
      const int   L     = 1024 >> si;
      const int   off2  = (si == 1) ? 1024 : (si == 2) ? 1536 : 1792;
      const float inv_s = (si == 1) ? 0.5f : (si == 2) ? 0.25f : 0.125f;
      #pragma unroll
      for (int kk = 0; kk < 4; kk++) {
        float srcp = ((float)(k0 + kk) + 0.5f) * inv_s - 0.5f;
        srcp = fminf(fmaxf(srcp, 0.f), (float)(L - 1));
        const int i0 = (int)floorf(srcp);
        const int i1 = min(i0 + 1, L - 1);
        const float w = srcp - (float)i0;
        res[kk] += (1.f - w) * bf2f(p2[off2 + i0]) + w * bf2f(p2[off2 + i1]);
      }
    }
    *(float4*)(ab + (size_t)idx * 4) =
        make_float4(res[0] * 0.25f, res[1] * 0.25f,
                    res[2] * 0.25f, res[3] * 0.25f);
  }
}

// ---------------------------------------------------------------------------
extern "C" void kernel_launch(void* const* d_in, const int* in_sizes, int n_in,
                              void* d_out, int out_size, void* d_ws, size_t ws_size,
                              hipStream_t stream) {
  (void)in_sizes; (void)n_in; (void)out_size; (void)ws_size;
  const float* query = (const float*)d_in[0];
  const float* key   = (const float*)d_in[1];
  const float* value = (const float*)d_in[2];
  const float* W     = (const float*)d_in[3];
  const float* b     = (const float*)d_in[4];
  float* out = (float*)d_out;

  float* pv = (float*)d_ws;                                       // 15.7 MB fp32
  unsigned short* projB = (unsigned short*)(pv + (size_t)NBH * HEAD_K); // 7.9 MB bf16
  unsigned short* mpvB  = projB + (size_t)NBH * HEAD_K;                 // 7.9 MB bf16

  pool_project_kernel<<<NBH * 30, 256, 0, stream>>>(key, value, W, b, projB, pv);
  mpv_pack_kernel<<<(NBH * NCHUNK) / 256, 256, 0, stream>>>(pv, mpvB);
  fused_attn_kernel<<<NBH * 64, 256, 0, stream>>>(query, projB, mpvB, out);
}